// Round 5
// baseline (189.351 us; speedup 1.0000x reference)
//
#include <hip/hip_runtime.h>

// Problem constants (match reference.py)
constexpr int NN   = 50000;      // nodes
constexpr int KDEG = 32;         // neighbors per node
constexpr int NE   = NN * KDEG;  // edges = 1,600,000
constexpr int NB   = 1024;       // batch pairs
constexpr int NH   = 64;         // MLP hidden width

// Scalar-in/scalar-out 64-hidden MLP: out = sum_j relu(x*w1[j]+b1[j])*w2[j] + b2
__device__ __forceinline__ float mlp64(float x,
                                       const float* __restrict__ w1,
                                       const float* __restrict__ b1,
                                       const float* __restrict__ w2,
                                       float b2) {
    float acc = 0.0f;
#pragma unroll 8
    for (int j = 0; j < NH; ++j) {
        float h = fmaxf(fmaf(x, w1[j], b1[j]), 0.0f);
        acc = fmaf(h, w2[j], acc);
    }
    return acc + b2;
}

// Stage 1: per-edge MLP + scatter-add into nsf0 (== d_out[NB..NB+NN), pre-zeroed)
__global__ void edge_kernel(const int* __restrict__ nbr,
                            const float* __restrict__ ew,
                            const float* __restrict__ w1,
                            const float* __restrict__ b1,
                            const float* __restrict__ w2,
                            const float* __restrict__ b2p,
                            float* __restrict__ nsf0) {
    int e = blockIdx.x * blockDim.x + threadIdx.x;
    if (e >= NE) return;
    float val = mlp64(ew[e], w1, b1, w2, b2p[0]);
    atomicAdd(&nsf0[nbr[e]], val);
}

// Stage 2: per-node MLP, in place: nsf[n] = fn_mlp(nsf0[n])
__global__ void node_kernel(float* __restrict__ nsf,
                            const float* __restrict__ w1,
                            const float* __restrict__ b1,
                            const float* __restrict__ w2,
                            const float* __restrict__ b2p) {
    int n = blockIdx.x * blockDim.x + threadIdx.x;
    if (n >= NN) return;
    nsf[n] = mlp64(nsf[n], w1, b1, w2, b2p[0]);
}

// Stage 3: one 64-lane wave per pair b.
// Lanes 0..31 hold neighbors[src[b]], lanes 32..63 hold neighbors[dst[b]].
// mat_src[b][c] = cntS(c)*nsf[c]  =>
//   out_struct     = sum_{src lanes} cntD(id)*v^2
//   ||mat_src||^2  = sum_{src lanes} cntS(id)*v^2
//   ||mat_dst||^2  = sum_{dst lanes} cntD(id)*v^2
// (dropout mask contribution to the norms is ~1e-8 relative — ignored)
__global__ void pair_kernel(const int* __restrict__ nbr,
                            const int* __restrict__ src,
                            const int* __restrict__ dst,
                            const float* __restrict__ nsf,
                            const float* __restrict__ w1,
                            const float* __restrict__ b1,
                            const float* __restrict__ w2,
                            const float* __restrict__ b2p,
                            float* __restrict__ out) {
    int wave = (blockIdx.x * blockDim.x + threadIdx.x) >> 6;
    int lane = threadIdx.x & 63;
    if (wave >= NB) return;

    bool isSrc = lane < 32;
    int node = isSrc ? src[wave] : dst[wave];
    int id = nbr[node * KDEG + (lane & 31)];
    float v = nsf[id];

    int cntS = 0, cntD = 0;
#pragma unroll
    for (int k = 0; k < 32; ++k) {
        int o = __shfl(id, k, 64);
        cntS += (o == id) ? 1 : 0;
    }
#pragma unroll
    for (int k = 32; k < 64; ++k) {
        int o = __shfl(id, k, 64);
        cntD += (o == id) ? 1 : 0;
    }

    float v2 = v * v;
    float dotc = isSrc ? (float)cntD * v2 : 0.0f;
    float ns   = isSrc ? (float)cntS * v2 : 0.0f;
    float nd   = isSrc ? 0.0f : (float)cntD * v2;

#pragma unroll
    for (int off = 32; off > 0; off >>= 1) {
        dotc += __shfl_xor(dotc, off, 64);
        ns   += __shfl_xor(ns,   off, 64);
        nd   += __shfl_xor(nd,   off, 64);
    }

    if (lane == 0) {
        float D = sqrtf(ns) * sqrtf(nd);
        float x = dotc / fmaxf(D, 1e-30f);
        out[wave] = mlp64(x, w1, b1, w2, b2p[0]);
    }
}

extern "C" void kernel_launch(void* const* d_in, const int* in_sizes, int n_in,
                              void* d_out, int out_size, void* d_ws, size_t ws_size,
                              hipStream_t stream) {
    const int*   nbr    = (const int*)  d_in[0];
    const float* edge_w = (const float*)d_in[1];
    const int*   src    = (const int*)  d_in[2];
    const int*   dst    = (const int*)  d_in[3];
    const float* fe_w1  = (const float*)d_in[4];
    const float* fe_b1  = (const float*)d_in[5];
    const float* fe_w2  = (const float*)d_in[6];
    const float* fe_b2  = (const float*)d_in[7];
    const float* fn_w1  = (const float*)d_in[8];
    const float* fn_b1  = (const float*)d_in[9];
    const float* fn_w2  = (const float*)d_in[10];
    const float* fn_b2  = (const float*)d_in[11];
    const float* gp_w1  = (const float*)d_in[12];
    const float* gp_b1  = (const float*)d_in[13];
    const float* gp_w2  = (const float*)d_in[14];
    const float* gp_b2  = (const float*)d_in[15];

    float* out   = (float*)d_out;        // [0..NB): out_struct_n
    float* nsf   = (float*)d_out + NB;   // [NB..NB+NN): nsf (output 2, also used as scratch)

    // Zero the nsf accumulator region (harness poisons d_out with 0xAA each call)
    hipMemsetAsync(nsf, 0, (size_t)NN * sizeof(float), stream);

    edge_kernel<<<NE / 256, 256, 0, stream>>>(nbr, edge_w, fe_w1, fe_b1, fe_w2, fe_b2, nsf);
    node_kernel<<<(NN + 255) / 256, 256, 0, stream>>>(nsf, fn_w1, fn_b1, fn_w2, fn_b2);
    pair_kernel<<<(NB * 64) / 256, 256, 0, stream>>>(nbr, src, dst, nsf,
                                                     gp_w1, gp_b1, gp_w2, gp_b2, out);
}

// Round 6
// 138.184 us; speedup vs baseline: 1.3703x; 1.3703x over previous
//
#include <hip/hip_runtime.h>

// Problem constants (match reference.py)
constexpr int NN   = 50000;      // nodes
constexpr int KDEG = 32;         // neighbors per node
constexpr int NE   = NN * KDEG;  // edges = 1,600,000
constexpr int NB   = 1024;       // batch pairs
constexpr int NH   = 64;         // MLP hidden width

// Binned-scatter parameters
constexpr int BINS = (NN + 255) >> 8;            // 196 bins of 256 nodes
constexpr int CAP  = 10240;                      // per-bin capacity (avg 8163, max ~8600)
constexpr int EPB  = 2048;                       // edges per scatter block
constexpr int SCT_BLOCKS = (NE + EPB - 1) / EPB; // 782

// Scalar-in/scalar-out 64-hidden MLP
__device__ __forceinline__ float mlp64(float x,
                                       const float* __restrict__ w1,
                                       const float* __restrict__ b1,
                                       const float* __restrict__ w2,
                                       float b2) {
    float acc = 0.0f;
#pragma unroll 8
    for (int j = 0; j < NH; ++j) {
        float h = fmaxf(fmaf(x, w1[j], b1[j]), 0.0f);
        acc = fmaf(h, w2[j], acc);
    }
    return acc + b2;
}

// ---------------- Fast path: binned counting-scatter ----------------
// Block sorts EPB edges by node-bin in LDS, claims global space with ONE
// atomic per (block,bin), writes (val,node) pairs contiguously per bin.
__global__ __launch_bounds__(256) void scatter_kernel(
        const int* __restrict__ nbr, const float* __restrict__ ew,
        const float* __restrict__ w1, const float* __restrict__ b1,
        const float* __restrict__ w2, const float* __restrict__ b2p,
        uint2* __restrict__ sorted, int* __restrict__ alloc) {
    __shared__ uint2 stage[EPB];        // 16 KB
    __shared__ int   hist[BINS];
    __shared__ int   lbase[BINS];
    __shared__ int   gbase[BINS];
    __shared__ int   scan[256];

    const int tid = threadIdx.x;
    for (int i = tid; i < BINS; i += 256) hist[i] = 0;
    __syncthreads();

    const int e0 = blockIdx.x * EPB;
    const float b2 = b2p[0];
    float val[8]; int node[8]; int loc[8];
#pragma unroll
    for (int j = 0; j < 8; ++j) {
        int e = e0 + tid + j * 256;
        if (e < NE) {
            node[j] = nbr[e];
            val[j]  = mlp64(ew[e], w1, b1, w2, b2);
            loc[j]  = atomicAdd(&hist[node[j] >> 8], 1);
        } else {
            node[j] = -1;
        }
    }
    __syncthreads();

    // Inclusive Hillis-Steele scan over bin counts -> exclusive lbase
    int v = (tid < BINS) ? hist[tid] : 0;
    scan[tid] = v;
    __syncthreads();
    for (int off = 1; off < 256; off <<= 1) {
        int t = (tid >= off) ? scan[tid - off] : 0;
        __syncthreads();
        scan[tid] += t;
        __syncthreads();
    }
    if (tid < BINS) lbase[tid] = scan[tid] - hist[tid];
    __syncthreads();

    // Place edges into block-local sorted staging
#pragma unroll
    for (int j = 0; j < 8; ++j) {
        if (node[j] >= 0) {
            int b = node[j] >> 8;
            stage[lbase[b] + loc[j]] = make_uint2(__float_as_uint(val[j]), (unsigned)node[j]);
        }
    }
    // Claim global space: one atomic per (block, non-empty bin)
    if (tid < BINS) {
        int c = hist[tid];
        gbase[tid] = c ? atomicAdd(&alloc[tid], c) : 0;
    }
    __syncthreads();

    // Copy staged runs to global bin regions (coalesced within runs)
    const int total = lbase[BINS - 1] + hist[BINS - 1];
    for (int j = tid; j < total; j += 256) {
        uint2 p = stage[j];
        int b   = (int)(p.y >> 8);
        int dst = gbase[b] + (j - lbase[b]);
        if (dst < CAP) sorted[(size_t)b * CAP + dst] = p;
    }
}

// Per-bin reduce (LDS atomics) + fn-MLP, non-atomic final write.
__global__ __launch_bounds__(256) void reduce_kernel(
        const uint2* __restrict__ sorted, const int* __restrict__ alloc,
        const float* __restrict__ w1, const float* __restrict__ b1,
        const float* __restrict__ w2, const float* __restrict__ b2p,
        float* __restrict__ nsf) {
    __shared__ float acc[256];
    const int b = blockIdx.x, tid = threadIdx.x;
    acc[tid] = 0.0f;
    __syncthreads();
    const int cnt = min(alloc[b], CAP);
    const uint2* p = sorted + (size_t)b * CAP;
    for (int i = tid; i < cnt; i += 256) {
        uint2 e = p[i];
        atomicAdd(&acc[e.y & 255u], __uint_as_float(e.x));
    }
    __syncthreads();
    const int n = (b << 8) + tid;
    if (n < NN) nsf[n] = mlp64(acc[tid], w1, b1, w2, b2p[0]);
}

// ---------------- Fallback path (ws too small): original kernels ----------------
__global__ void edge_kernel(const int* __restrict__ nbr, const float* __restrict__ ew,
                            const float* __restrict__ w1, const float* __restrict__ b1,
                            const float* __restrict__ w2, const float* __restrict__ b2p,
                            float* __restrict__ nsf0) {
    int e = blockIdx.x * blockDim.x + threadIdx.x;
    if (e >= NE) return;
    float val = mlp64(ew[e], w1, b1, w2, b2p[0]);
    atomicAdd(&nsf0[nbr[e]], val);
}

__global__ void node_kernel(float* __restrict__ nsf,
                            const float* __restrict__ w1, const float* __restrict__ b1,
                            const float* __restrict__ w2, const float* __restrict__ b2p) {
    int n = blockIdx.x * blockDim.x + threadIdx.x;
    if (n >= NN) return;
    nsf[n] = mlp64(nsf[n], w1, b1, w2, b2p[0]);
}

// ---------------- Stage 3: one 64-lane wave per pair ----------------
__global__ void pair_kernel(const int* __restrict__ nbr,
                            const int* __restrict__ src, const int* __restrict__ dst,
                            const float* __restrict__ nsf,
                            const float* __restrict__ w1, const float* __restrict__ b1,
                            const float* __restrict__ w2, const float* __restrict__ b2p,
                            float* __restrict__ out) {
    int wave = (blockIdx.x * blockDim.x + threadIdx.x) >> 6;
    int lane = threadIdx.x & 63;
    if (wave >= NB) return;

    bool isSrc = lane < 32;
    int node = isSrc ? src[wave] : dst[wave];
    int id = nbr[node * KDEG + (lane & 31)];
    float v = nsf[id];

    int cntS = 0, cntD = 0;
#pragma unroll
    for (int k = 0; k < 32; ++k) {
        int o = __shfl(id, k, 64);
        cntS += (o == id) ? 1 : 0;
    }
#pragma unroll
    for (int k = 32; k < 64; ++k) {
        int o = __shfl(id, k, 64);
        cntD += (o == id) ? 1 : 0;
    }

    float v2 = v * v;
    float dotc = isSrc ? (float)cntD * v2 : 0.0f;
    float ns   = isSrc ? (float)cntS * v2 : 0.0f;
    float nd   = isSrc ? 0.0f : (float)cntD * v2;

#pragma unroll
    for (int off = 32; off > 0; off >>= 1) {
        dotc += __shfl_xor(dotc, off, 64);
        ns   += __shfl_xor(ns,   off, 64);
        nd   += __shfl_xor(nd,   off, 64);
    }

    if (lane == 0) {
        float D = sqrtf(ns) * sqrtf(nd);
        float x = dotc / fmaxf(D, 1e-30f);
        out[wave] = mlp64(x, w1, b1, w2, b2p[0]);
    }
}

extern "C" void kernel_launch(void* const* d_in, const int* in_sizes, int n_in,
                              void* d_out, int out_size, void* d_ws, size_t ws_size,
                              hipStream_t stream) {
    const int*   nbr    = (const int*)  d_in[0];
    const float* edge_w = (const float*)d_in[1];
    const int*   src    = (const int*)  d_in[2];
    const int*   dst    = (const int*)  d_in[3];
    const float* fe_w1  = (const float*)d_in[4];
    const float* fe_b1  = (const float*)d_in[5];
    const float* fe_w2  = (const float*)d_in[6];
    const float* fe_b2  = (const float*)d_in[7];
    const float* fn_w1  = (const float*)d_in[8];
    const float* fn_b1  = (const float*)d_in[9];
    const float* fn_w2  = (const float*)d_in[10];
    const float* fn_b2  = (const float*)d_in[11];
    const float* gp_w1  = (const float*)d_in[12];
    const float* gp_b1  = (const float*)d_in[13];
    const float* gp_w2  = (const float*)d_in[14];
    const float* gp_b2  = (const float*)d_in[15];

    float* out = (float*)d_out;       // [0..NB): out_struct_n
    float* nsf = (float*)d_out + NB;  // [NB..NB+NN): nsf (output 2)

    const size_t sorted_bytes = (size_t)BINS * CAP * sizeof(uint2); // ~16.06 MB
    const size_t need = sorted_bytes + BINS * sizeof(int);

    if (ws_size >= need) {
        uint2* sorted = (uint2*)d_ws;
        int*   alloc  = (int*)((char*)d_ws + sorted_bytes);
        hipMemsetAsync(alloc, 0, BINS * sizeof(int), stream);
        scatter_kernel<<<SCT_BLOCKS, 256, 0, stream>>>(nbr, edge_w,
                                                       fe_w1, fe_b1, fe_w2, fe_b2,
                                                       sorted, alloc);
        reduce_kernel<<<BINS, 256, 0, stream>>>(sorted, alloc,
                                                fn_w1, fn_b1, fn_w2, fn_b2, nsf);
    } else {
        hipMemsetAsync(nsf, 0, (size_t)NN * sizeof(float), stream);
        edge_kernel<<<NE / 256, 256, 0, stream>>>(nbr, edge_w, fe_w1, fe_b1, fe_w2, fe_b2, nsf);
        node_kernel<<<(NN + 255) / 256, 256, 0, stream>>>(nsf, fn_w1, fn_b1, fn_w2, fn_b2);
    }

    pair_kernel<<<(NB * 64) / 256, 256, 0, stream>>>(nbr, src, dst, nsf,
                                                     gp_w1, gp_b1, gp_w2, gp_b2, out);
}

// Round 8
// 137.771 us; speedup vs baseline: 1.3744x; 1.0030x over previous
//
#include <hip/hip_runtime.h>

// Problem constants (match reference.py)
constexpr int NN   = 50000;      // nodes
constexpr int KDEG = 32;         // neighbors per node
constexpr int NE   = NN * KDEG;  // edges = 1,600,000
constexpr int NB   = 1024;       // batch pairs
constexpr int NH   = 64;         // MLP hidden width

// Binned-scatter parameters
constexpr int BINS = (NN + 255) >> 8;            // 196 bins of 256 nodes
constexpr int CAP  = 10240;                      // per-bin capacity (mean 8192, max ~8600)
constexpr int EPB  = 2048;                       // edges per scatter block
constexpr int SCT_BLOCKS = (NE + EPB - 1) / EPB; // 782

// Scalar-in/scalar-out 64-hidden MLP
__device__ __forceinline__ float mlp64(float x,
                                       const float* __restrict__ w1,
                                       const float* __restrict__ b1,
                                       const float* __restrict__ w2,
                                       float b2) {
    float acc = 0.0f;
#pragma unroll 8
    for (int j = 0; j < NH; ++j) {
        float h = fmaxf(fmaf(x, w1[j], b1[j]), 0.0f);
        acc = fmaf(h, w2[j], acc);
    }
    return acc + b2;
}

// ---------------- Fast path: binned counting-scatter ----------------
// Block sorts EPB edges by node-bin in LDS, claims global space with ONE
// atomic per (block,bin), writes val(4B)+idx(1B) contiguously per bin.
__global__ __launch_bounds__(256) void scatter_kernel(
        const int* __restrict__ nbr, const float* __restrict__ ew,
        const float* __restrict__ w1, const float* __restrict__ b1,
        const float* __restrict__ w2, const float* __restrict__ b2p,
        float* __restrict__ sortedV, unsigned char* __restrict__ sortedB,
        int* __restrict__ alloc) {
    __shared__ float          sV[EPB];        // 8 KB staged values
    __shared__ unsigned short sN[EPB];        // 4 KB staged node ids (node < 65536)
    __shared__ int hist[BINS];
    __shared__ int lbase[BINS + 1];
    __shared__ int gbase[BINS];

    const int tid = threadIdx.x;
    for (int i = tid; i < BINS; i += 256) hist[i] = 0;
    __syncthreads();

    const int e0 = blockIdx.x * EPB;
    const float b2 = b2p[0];
    float val[8]; int node[8]; int loc[8];
#pragma unroll
    for (int j = 0; j < 8; ++j) {
        int e = e0 + tid + j * 256;
        if (e < NE) {
            node[j] = nbr[e];
            val[j]  = mlp64(ew[e], w1, b1, w2, b2);
            loc[j]  = atomicAdd(&hist[node[j] >> 8], 1);
        } else {
            node[j] = -1;
        }
    }
    __syncthreads();

    // Exclusive scan over 196 bin counts: one wave, 4 bins/lane, shfl scan.
    if (tid < 64) {
        int b0 = tid * 4;
        int c0 = (b0 + 0 < BINS) ? hist[b0 + 0] : 0;
        int c1 = (b0 + 1 < BINS) ? hist[b0 + 1] : 0;
        int c2 = (b0 + 2 < BINS) ? hist[b0 + 2] : 0;
        int c3 = (b0 + 3 < BINS) ? hist[b0 + 3] : 0;
        int s = c0 + c1 + c2 + c3;
        int p = s;
#pragma unroll
        for (int off = 1; off < 64; off <<= 1) {
            int t = __shfl_up(p, off, 64);
            if (tid >= off) p += t;
        }
        int excl = p - s;
        if (b0 + 0 < BINS) lbase[b0 + 0] = excl;
        if (b0 + 1 < BINS) lbase[b0 + 1] = excl + c0;
        if (b0 + 2 < BINS) lbase[b0 + 2] = excl + c0 + c1;
        if (b0 + 3 < BINS) lbase[b0 + 3] = excl + c0 + c1 + c2;
        if (tid == 63) lbase[BINS] = p;   // total staged count
    }
    __syncthreads();

    // Claim global space early (one atomic per non-empty bin) so the atomic
    // latency overlaps the LDS staging writes below.
    if (tid < BINS) {
        int c = hist[tid];
        gbase[tid] = c ? atomicAdd(&alloc[tid], c) : 0;
    }

    // Place edges into block-local bin-sorted staging
#pragma unroll
    for (int j = 0; j < 8; ++j) {
        if (node[j] >= 0) {
            int b = node[j] >> 8;
            int p = lbase[b] + loc[j];
            sV[p] = val[j];
            sN[p] = (unsigned short)node[j];
        }
    }
    __syncthreads();

    // Copy staged runs to global bin regions
    const int total = lbase[BINS];
    for (int j = tid; j < total; j += 256) {
        int n   = sN[j];
        int b   = n >> 8;
        int dst = gbase[b] + (j - lbase[b]);
        if (dst < CAP) {
            sortedV[(size_t)b * CAP + dst] = sV[j];
            sortedB[(size_t)b * CAP + dst] = (unsigned char)(n & 255);
        }
    }
}

// Per-bin reduce (LDS atomics) + fn-MLP, non-atomic final write.
__global__ __launch_bounds__(512) void reduce_kernel(
        const float* __restrict__ sortedV, const unsigned char* __restrict__ sortedB,
        const int* __restrict__ alloc,
        const float* __restrict__ w1, const float* __restrict__ b1,
        const float* __restrict__ w2, const float* __restrict__ b2p,
        float* __restrict__ nsf) {
    __shared__ float acc[256];
    const int b = blockIdx.x, tid = threadIdx.x;
    if (tid < 256) acc[tid] = 0.0f;
    __syncthreads();
    const int cnt = min(alloc[b], CAP);
    const float* pv = sortedV + (size_t)b * CAP;
    const unsigned char* pb = sortedB + (size_t)b * CAP;
    for (int i = tid; i < cnt; i += 512) {
        atomicAdd(&acc[pb[i]], pv[i]);
    }
    __syncthreads();
    if (tid < 256) {
        const int n = (b << 8) + tid;
        if (n < NN) nsf[n] = mlp64(acc[tid], w1, b1, w2, b2p[0]);
    }
}

// ---------------- Fallback path (ws too small): original kernels ----------------
__global__ void edge_kernel(const int* __restrict__ nbr, const float* __restrict__ ew,
                            const float* __restrict__ w1, const float* __restrict__ b1,
                            const float* __restrict__ w2, const float* __restrict__ b2p,
                            float* __restrict__ nsf0) {
    int e = blockIdx.x * blockDim.x + threadIdx.x;
    if (e >= NE) return;
    float val = mlp64(ew[e], w1, b1, w2, b2p[0]);
    atomicAdd(&nsf0[nbr[e]], val);
}

__global__ void node_kernel(float* __restrict__ nsf,
                            const float* __restrict__ w1, const float* __restrict__ b1,
                            const float* __restrict__ w2, const float* __restrict__ b2p) {
    int n = blockIdx.x * blockDim.x + threadIdx.x;
    if (n >= NN) return;
    nsf[n] = mlp64(nsf[n], w1, b1, w2, b2p[0]);
}

// ---------------- Stage 3: one 64-lane wave per pair ----------------
__global__ void pair_kernel(const int* __restrict__ nbr,
                            const int* __restrict__ src, const int* __restrict__ dst,
                            const float* __restrict__ nsf,
                            const float* __restrict__ w1, const float* __restrict__ b1,
                            const float* __restrict__ w2, const float* __restrict__ b2p,
                            float* __restrict__ out) {
    int wave = (blockIdx.x * blockDim.x + threadIdx.x) >> 6;
    int lane = threadIdx.x & 63;
    if (wave >= NB) return;

    bool isSrc = lane < 32;
    int node = isSrc ? src[wave] : dst[wave];
    int id = nbr[node * KDEG + (lane & 31)];
    float v = nsf[id];

    int cntS = 0, cntD = 0;
#pragma unroll
    for (int k = 0; k < 32; ++k) {
        int o = __shfl(id, k, 64);
        cntS += (o == id) ? 1 : 0;
    }
#pragma unroll
    for (int k = 32; k < 64; ++k) {
        int o = __shfl(id, k, 64);
        cntD += (o == id) ? 1 : 0;
    }

    float v2 = v * v;
    float dotc = isSrc ? (float)cntD * v2 : 0.0f;
    float ns   = isSrc ? (float)cntS * v2 : 0.0f;
    float nd   = isSrc ? 0.0f : (float)cntD * v2;

#pragma unroll
    for (int off = 32; off > 0; off >>= 1) {
        dotc += __shfl_xor(dotc, off, 64);
        ns   += __shfl_xor(ns,   off, 64);
        nd   += __shfl_xor(nd,   off, 64);
    }

    if (lane == 0) {
        float D = sqrtf(ns) * sqrtf(nd);
        float x = dotc / fmaxf(D, 1e-30f);
        out[wave] = mlp64(x, w1, b1, w2, b2p[0]);
    }
}

extern "C" void kernel_launch(void* const* d_in, const int* in_sizes, int n_in,
                              void* d_out, int out_size, void* d_ws, size_t ws_size,
                              hipStream_t stream) {
    const int*   nbr    = (const int*)  d_in[0];
    const float* edge_w = (const float*)d_in[1];
    const int*   src    = (const int*)  d_in[2];
    const int*   dst    = (const int*)  d_in[3];
    const float* fe_w1  = (const float*)d_in[4];
    const float* fe_b1  = (const float*)d_in[5];
    const float* fe_w2  = (const float*)d_in[6];
    const float* fe_b2  = (const float*)d_in[7];
    const float* fn_w1  = (const float*)d_in[8];
    const float* fn_b1  = (const float*)d_in[9];
    const float* fn_w2  = (const float*)d_in[10];
    const float* fn_b2  = (const float*)d_in[11];
    const float* gp_w1  = (const float*)d_in[12];
    const float* gp_b1  = (const float*)d_in[13];
    const float* gp_w2  = (const float*)d_in[14];
    const float* gp_b2  = (const float*)d_in[15];

    float* out = (float*)d_out;       // [0..NB): out_struct_n
    float* nsf = (float*)d_out + NB;  // [NB..NB+NN): nsf (output 2)

    const size_t nEnt    = (size_t)BINS * CAP;
    const size_t v_bytes = nEnt * sizeof(float);                 // ~8.03 MB
    const size_t b_bytes = (nEnt + 255) & ~(size_t)255;          // ~2.01 MB
    const size_t need    = v_bytes + b_bytes + BINS * sizeof(int);

    if (ws_size >= need) {
        float*         sortedV = (float*)d_ws;
        unsigned char* sortedB = (unsigned char*)d_ws + v_bytes;
        int*           alloc   = (int*)((char*)d_ws + v_bytes + b_bytes);
        hipMemsetAsync(alloc, 0, BINS * sizeof(int), stream);
        scatter_kernel<<<SCT_BLOCKS, 256, 0, stream>>>(nbr, edge_w,
                                                       fe_w1, fe_b1, fe_w2, fe_b2,
                                                       sortedV, sortedB, alloc);
        reduce_kernel<<<BINS, 512, 0, stream>>>(sortedV, sortedB, alloc,
                                                fn_w1, fn_b1, fn_w2, fn_b2, nsf);
    } else {
        hipMemsetAsync(nsf, 0, (size_t)NN * sizeof(float), stream);
        edge_kernel<<<NE / 256, 256, 0, stream>>>(nbr, edge_w, fe_w1, fe_b1, fe_w2, fe_b2, nsf);
        node_kernel<<<(NN + 255) / 256, 256, 0, stream>>>(nsf, fn_w1, fn_b1, fn_w2, fn_b2);
    }

    pair_kernel<<<(NB * 64) / 256, 256, 0, stream>>>(nbr, src, dst, nsf,
                                                     gp_w1, gp_b1, gp_w2, gp_b2, out);
}

// Round 11
// 126.686 us; speedup vs baseline: 1.4946x; 1.0875x over previous
//
#include <hip/hip_runtime.h>

// Problem constants (match reference.py)
constexpr int NN   = 50000;      // nodes
constexpr int KDEG = 32;         // neighbors per node
constexpr int NE   = NN * KDEG;  // edges = 1,600,000
constexpr int NB   = 1024;       // batch pairs
constexpr int NH   = 64;         // MLP hidden width

// Binned-scatter parameters
constexpr int BINS = (NN + 255) >> 8;            // 196 bins of 256 nodes
constexpr int EPB  = 2048;                       // edges per scatter block
constexpr int SCT_BLOCKS = (NE + EPB - 1) / EPB; // 782
constexpr int CAP2 = 40;                         // slots per (bin,block) cell; mean 10.4, P(>40)~1e-12

// Scalar-in/scalar-out 64-hidden MLP (two accumulators -> half the dep chain)
__device__ __forceinline__ float mlp64(float x,
                                       const float* __restrict__ w1,
                                       const float* __restrict__ b1,
                                       const float* __restrict__ w2,
                                       float b2) {
    float a0 = 0.0f, a1 = 0.0f;
#pragma unroll 8
    for (int j = 0; j < NH; j += 2) {
        float h0 = fmaxf(fmaf(x, w1[j],     b1[j]),     0.0f);
        float h1 = fmaxf(fmaf(x, w1[j + 1], b1[j + 1]), 0.0f);
        a0 = fmaf(h0, w2[j],     a0);
        a1 = fmaf(h1, w2[j + 1], a1);
    }
    return a0 + a1 + b2;
}

// ---------------- Fast path: deterministic binned scatter (ZERO global atomics) ----------
// Block sorts its EPB edges by node-bin in LDS, then writes val(4B)+idx(1B) into its OWN
// fixed cell sorted[bin][block][CAP2]; per-cell count written plainly to cnt[bin][block].
__global__ __launch_bounds__(256) void scatter_kernel(
        const int* __restrict__ nbr, const float* __restrict__ ew,
        const float* __restrict__ w1, const float* __restrict__ b1,
        const float* __restrict__ w2, const float* __restrict__ b2p,
        float* __restrict__ sortedV, unsigned char* __restrict__ sortedB,
        unsigned char* __restrict__ cnt) {
    __shared__ float          sV[EPB];        // 8 KB staged values
    __shared__ unsigned short sN[EPB];        // 4 KB staged node ids (node < 65536)
    __shared__ int hist[BINS];
    __shared__ int lbase[BINS + 1];

    const int tid = threadIdx.x;
    const int blk = blockIdx.x;
    for (int i = tid; i < BINS; i += 256) hist[i] = 0;
    __syncthreads();

    const int e0 = blk * EPB;
    const float b2 = b2p[0];
    float val[8]; int node[8]; int loc[8];
#pragma unroll
    for (int j = 0; j < 8; ++j) {
        int e = e0 + tid + j * 256;
        if (e < NE) {
            node[j] = nbr[e];
            val[j]  = mlp64(ew[e], w1, b1, w2, b2);
            loc[j]  = atomicAdd(&hist[node[j] >> 8], 1);   // LDS atomic only
        } else {
            node[j] = -1;
        }
    }
    __syncthreads();

    // Exclusive scan over 196 bin counts: one wave, 4 bins/lane, shfl scan.
    if (tid < 64) {
        int b0 = tid * 4;
        int c0 = (b0 + 0 < BINS) ? hist[b0 + 0] : 0;
        int c1 = (b0 + 1 < BINS) ? hist[b0 + 1] : 0;
        int c2 = (b0 + 2 < BINS) ? hist[b0 + 2] : 0;
        int c3 = (b0 + 3 < BINS) ? hist[b0 + 3] : 0;
        int s = c0 + c1 + c2 + c3;
        int p = s;
#pragma unroll
        for (int off = 1; off < 64; off <<= 1) {
            int t = __shfl_up(p, off, 64);
            if (tid >= off) p += t;
        }
        int excl = p - s;
        if (b0 + 0 < BINS) lbase[b0 + 0] = excl;
        if (b0 + 1 < BINS) lbase[b0 + 1] = excl + c0;
        if (b0 + 2 < BINS) lbase[b0 + 2] = excl + c0 + c1;
        if (b0 + 3 < BINS) lbase[b0 + 3] = excl + c0 + c1 + c2;
        if (tid == 63) lbase[BINS] = p;   // total staged count
    }
    // Write per-cell counts (plain stores; deterministic layout => no claim needed)
    if (tid < BINS) {
        cnt[(size_t)tid * SCT_BLOCKS + blk] =
            (unsigned char)min(hist[tid], CAP2);
    }
    // REQUIRED: lbase[] is written by wave 0 only; all waves read it below.
    // (R8's missing barrier here was the correctness regression.)
    __syncthreads();

    // Place edges into block-local bin-sorted staging
#pragma unroll
    for (int j = 0; j < 8; ++j) {
        if (node[j] >= 0) {
            int b = node[j] >> 8;
            int p = lbase[b] + loc[j];
            sV[p] = val[j];
            sN[p] = (unsigned short)node[j];
        }
    }
    __syncthreads();

    // Copy staged runs to this block's fixed cells (runs contiguous => coalesced)
    const int total = lbase[BINS];
    for (int j = tid; j < total; j += 256) {
        int n    = sN[j];
        int b    = n >> 8;
        int slot = j - lbase[b];
        if (slot < CAP2) {
            size_t base = ((size_t)b * SCT_BLOCKS + blk) * CAP2 + slot;
            sortedV[base] = sV[j];
            sortedB[base] = (unsigned char)(n & 255);
        }
    }
}

// Per-bin reduce: 1024 threads; thread t walks cell (bin, block=t). LDS atomics only.
__global__ __launch_bounds__(1024) void reduce_kernel(
        const float* __restrict__ sortedV, const unsigned char* __restrict__ sortedB,
        const unsigned char* __restrict__ cnt,
        const float* __restrict__ w1, const float* __restrict__ b1,
        const float* __restrict__ w2, const float* __restrict__ b2p,
        float* __restrict__ nsf) {
    __shared__ float acc[256];
    const int bin = blockIdx.x, tid = threadIdx.x;
    if (tid < 256) acc[tid] = 0.0f;
    __syncthreads();
    for (int cell = tid; cell < SCT_BLOCKS; cell += 1024) {
        int c = cnt[(size_t)bin * SCT_BLOCKS + cell];
        size_t base = ((size_t)bin * SCT_BLOCKS + cell) * CAP2;
        for (int k = 0; k < c; ++k) {
            atomicAdd(&acc[sortedB[base + k]], sortedV[base + k]);
        }
    }
    __syncthreads();
    if (tid < 256) {
        const int n = (bin << 8) + tid;
        if (n < NN) nsf[n] = mlp64(acc[tid], w1, b1, w2, b2p[0]);
    }
}

// ---------------- Fallback path (ws too small): original kernels ----------------
__global__ void edge_kernel(const int* __restrict__ nbr, const float* __restrict__ ew,
                            const float* __restrict__ w1, const float* __restrict__ b1,
                            const float* __restrict__ w2, const float* __restrict__ b2p,
                            float* __restrict__ nsf0) {
    int e = blockIdx.x * blockDim.x + threadIdx.x;
    if (e >= NE) return;
    float val = mlp64(ew[e], w1, b1, w2, b2p[0]);
    atomicAdd(&nsf0[nbr[e]], val);
}

__global__ void node_kernel(float* __restrict__ nsf,
                            const float* __restrict__ w1, const float* __restrict__ b1,
                            const float* __restrict__ w2, const float* __restrict__ b2p) {
    int n = blockIdx.x * blockDim.x + threadIdx.x;
    if (n >= NN) return;
    nsf[n] = mlp64(nsf[n], w1, b1, w2, b2p[0]);
}

// ---------------- Stage 3: one 64-lane wave per pair ----------------
__global__ void pair_kernel(const int* __restrict__ nbr,
                            const int* __restrict__ src, const int* __restrict__ dst,
                            const float* __restrict__ nsf,
                            const float* __restrict__ w1, const float* __restrict__ b1,
                            const float* __restrict__ w2, const float* __restrict__ b2p,
                            float* __restrict__ out) {
    int wave = (blockIdx.x * blockDim.x + threadIdx.x) >> 6;
    int lane = threadIdx.x & 63;
    if (wave >= NB) return;

    bool isSrc = lane < 32;
    int node = isSrc ? src[wave] : dst[wave];
    int id = nbr[node * KDEG + (lane & 31)];
    float v = nsf[id];

    int cntS = 0, cntD = 0;
#pragma unroll
    for (int k = 0; k < 32; ++k) {
        int o = __shfl(id, k, 64);
        cntS += (o == id) ? 1 : 0;
    }
#pragma unroll
    for (int k = 32; k < 64; ++k) {
        int o = __shfl(id, k, 64);
        cntD += (o == id) ? 1 : 0;
    }

    float v2 = v * v;
    float dotc = isSrc ? (float)cntD * v2 : 0.0f;
    float ns   = isSrc ? (float)cntS * v2 : 0.0f;
    float nd   = isSrc ? 0.0f : (float)cntD * v2;

#pragma unroll
    for (int off = 32; off > 0; off >>= 1) {
        dotc += __shfl_xor(dotc, off, 64);
        ns   += __shfl_xor(ns,   off, 64);
        nd   += __shfl_xor(nd,   off, 64);
    }

    if (lane == 0) {
        float D = sqrtf(ns) * sqrtf(nd);
        float x = dotc / fmaxf(D, 1e-30f);
        out[wave] = mlp64(x, w1, b1, w2, b2p[0]);
    }
}

extern "C" void kernel_launch(void* const* d_in, const int* in_sizes, int n_in,
                              void* d_out, int out_size, void* d_ws, size_t ws_size,
                              hipStream_t stream) {
    const int*   nbr    = (const int*)  d_in[0];
    const float* edge_w = (const float*)d_in[1];
    const int*   src    = (const int*)  d_in[2];
    const int*   dst    = (const int*)  d_in[3];
    const float* fe_w1  = (const float*)d_in[4];
    const float* fe_b1  = (const float*)d_in[5];
    const float* fe_w2  = (const float*)d_in[6];
    const float* fe_b2  = (const float*)d_in[7];
    const float* fn_w1  = (const float*)d_in[8];
    const float* fn_b1  = (const float*)d_in[9];
    const float* fn_w2  = (const float*)d_in[10];
    const float* fn_b2  = (const float*)d_in[11];
    const float* gp_w1  = (const float*)d_in[12];
    const float* gp_b1  = (const float*)d_in[13];
    const float* gp_w2  = (const float*)d_in[14];
    const float* gp_b2  = (const float*)d_in[15];

    float* out = (float*)d_out;       // [0..NB): out_struct_n
    float* nsf = (float*)d_out + NB;  // [NB..NB+NN): nsf (output 2)

    const size_t nCells  = (size_t)BINS * SCT_BLOCKS;           // 153,272
    const size_t v_bytes = nCells * CAP2 * sizeof(float);       // ~24.5 MB
    const size_t b_bytes = (nCells * CAP2 + 255) & ~(size_t)255;// ~6.1 MB
    const size_t c_bytes = (nCells + 255) & ~(size_t)255;       // ~150 KB
    const size_t need    = v_bytes + b_bytes + c_bytes;

    if (ws_size >= need) {
        float*         sortedV = (float*)d_ws;
        unsigned char* sortedB = (unsigned char*)d_ws + v_bytes;
        unsigned char* cnt     = (unsigned char*)d_ws + v_bytes + b_bytes;
        scatter_kernel<<<SCT_BLOCKS, 256, 0, stream>>>(nbr, edge_w,
                                                       fe_w1, fe_b1, fe_w2, fe_b2,
                                                       sortedV, sortedB, cnt);
        reduce_kernel<<<BINS, 1024, 0, stream>>>(sortedV, sortedB, cnt,
                                                 fn_w1, fn_b1, fn_w2, fn_b2, nsf);
    } else {
        hipMemsetAsync(nsf, 0, (size_t)NN * sizeof(float), stream);
        edge_kernel<<<NE / 256, 256, 0, stream>>>(nbr, edge_w, fe_w1, fe_b1, fe_w2, fe_b2, nsf);
        node_kernel<<<(NN + 255) / 256, 256, 0, stream>>>(nsf, fn_w1, fn_b1, fn_w2, fn_b2);
    }

    pair_kernel<<<(NB * 64) / 256, 256, 0, stream>>>(nbr, src, dst, nsf,
                                                     gp_w1, gp_b1, gp_w2, gp_b2, out);
}